// Round 2
// baseline (261.345 us; speedup 1.0000x reference)
//
#include <hip/hip_runtime.h>
#include <hip/hip_bf16.h>

typedef short s8v __attribute__((ext_vector_type(8)));   // 8 bf16 (4 VGPRs) MFMA A/B frag
typedef float f4v __attribute__((ext_vector_type(4)));   // 4 fp32 MFMA C/D frag

__device__ __forceinline__ unsigned int bfround(float f) {
    unsigned int x = __float_as_uint(f);
    return (x + 0x7fffu + ((x >> 16) & 1u)) >> 16;  // RNE fp32->bf16
}
__device__ __forceinline__ unsigned int pack2f(float lo, float hi) {
    return bfround(lo) | (bfround(hi) << 16);
}

// P[row][perm-col] (bf16) = feat[N,128] @ W1[whalf:whalf+128, :] (+ bias)
// Column permutation: perm(t*16+m) = m*8+t  (m = lane&15, t = col-tile 0..7).
// Dot products downstream are permutation-invariant; edge kernel uses the same perm for W2.
// Wave-independent: no LDS, no barriers. One wave = one 16-row tile, all 128 cols.
__global__ __launch_bounds__(256, 2) void proj_kernel(
    const float* __restrict__ feat, const float* __restrict__ W1,
    const float* __restrict__ bias, int whalf,
    uint4* __restrict__ P, int ntiles)
{
    const int lane = threadIdx.x & 63;
    const int m    = lane & 15;      // A-row / B-col index within tile
    const int q    = lane >> 4;      // quad: selects 8-chunk of K

    // One-time B fragments for all 8 column tiles (W1 is 128KB, L2-hot).
    // B[k][n]: n = t*16+m, k = c*32 + q*8 + j.
    s8v  bfrag[8][4];
    float bias_v[8];
    #pragma unroll
    for (int t = 0; t < 8; ++t) {
        int col = t * 16 + m;
        bias_v[t] = bias ? bias[col] : 0.0f;
        #pragma unroll
        for (int c = 0; c < 4; ++c) {
            s8v bf;
            #pragma unroll
            for (int j = 0; j < 8; ++j) {
                int k = c * 32 + q * 8 + j;
                bf[j] = (short)bfround(W1[(size_t)(whalf + k) * 128 + col]);
            }
            bfrag[t][c] = bf;
        }
    }

    const int wid = (blockIdx.x * 256 + threadIdx.x) >> 6;
    const int nw  = (gridDim.x * 256) >> 6;

    for (int tile = wid; tile < ntiles; tile += nw) {
        const float4* arow = (const float4*)feat + (size_t)tile * 16 * 32;

        // A loads: lane reads A[m][c*32+q*8 .. +8] = 2 float4 per c.
        // Per instruction: 16 rows x 128B contiguous K-segments — cache-line perfect.
        float4 a[4][2];
        #pragma unroll
        for (int c = 0; c < 4; ++c) {
            a[c][0] = arow[m * 32 + c * 8 + q * 2 + 0];
            a[c][1] = arow[m * 32 + c * 8 + q * 2 + 1];
        }

        f4v acc[8];
        #pragma unroll
        for (int t = 0; t < 8; ++t)
            acc[t] = (f4v){bias_v[t], bias_v[t], bias_v[t], bias_v[t]};

        #pragma unroll
        for (int c = 0; c < 4; ++c) {
            s8v af;
            af[0] = (short)bfround(a[c][0].x); af[1] = (short)bfround(a[c][0].y);
            af[2] = (short)bfround(a[c][0].z); af[3] = (short)bfround(a[c][0].w);
            af[4] = (short)bfround(a[c][1].x); af[5] = (short)bfround(a[c][1].y);
            af[6] = (short)bfround(a[c][1].z); af[7] = (short)bfround(a[c][1].w);
            #pragma unroll
            for (int t = 0; t < 8; ++t)
                acc[t] = __builtin_amdgcn_mfma_f32_16x16x32_bf16(af, bfrag[t][c], acc[t], 0, 0, 0);
        }

        // C/D layout: col = t*16+m, row = q*4 + r  [m89/m91 verified].
        // Perm store: lane packs t=0..7 for each r -> 8 consecutive bf16 at perm-col m*8.
        // One uint4 store per r; per instruction: 4 rows x 256B contiguous.
        #pragma unroll
        for (int r = 0; r < 4; ++r) {
            uint4 wv;
            wv.x = pack2f(acc[0][r], acc[1][r]);
            wv.y = pack2f(acc[2][r], acc[3][r]);
            wv.z = pack2f(acc[4][r], acc[5][r]);
            wv.w = pack2f(acc[6][r], acc[7][r]);
            int row = tile * 16 + q * 4 + r;
            P[(size_t)row * 16 + m] = wv;
        }
    }
}

// out[e] = relu(Pu[src[e]] + Pm[dst[e]]) . W2 + b2   (b1 folded into Pm; perm'd dims)
// 16 lanes per edge (uint4 = 8 packed bf16 dims per lane), 16 edges per wave.
__global__ __launch_bounds__(256) void edge_kernel(
    const int* __restrict__ src, const int* __restrict__ dst,
    const uint4* __restrict__ Pu, const uint4* __restrict__ Pm,
    const float* __restrict__ W2, const float* __restrict__ b2,
    float* __restrict__ out)
{
    const int lane = threadIdx.x & 63;
    const int w    = threadIdx.x >> 6;
    const int L    = lane & 15;      // sub-lane within edge group
    const int g    = lane >> 4;      // edge group 0..3
    const int e0   = (blockIdx.x * 4 + w) * 16;

    // W2 at perm position L*8+j is original col j*16+L
    float w2v[8];
    #pragma unroll
    for (int j = 0; j < 8; ++j) w2v[j] = W2[j * 16 + L];

    const int sv = src[e0 + L];      // lane L holds indices of edge e0+L
    const int dv = dst[e0 + L];

    float res[4];
    #pragma unroll
    for (int i = 0; i < 4; ++i) {
        // group g, round i -> edge e0 + g*4 + i
        int su = __shfl(sv, g * 4 + i, 64);
        int du = __shfl(dv, g * 4 + i, 64);
        uint4 pu = Pu[su * 16 + L];   // 16B/lane, 4x256B segments per instr
        uint4 pm = Pm[du * 16 + L];
        float acc = 0.0f;
        {
            const unsigned int ua[4] = {pu.x, pu.y, pu.z, pu.w};
            const unsigned int ma[4] = {pm.x, pm.y, pm.z, pm.w};
            #pragma unroll
            for (int k = 0; k < 4; ++k) {
                float lo = __uint_as_float(ua[k] << 16)         + __uint_as_float(ma[k] << 16);
                float hi = __uint_as_float(ua[k] & 0xffff0000u) + __uint_as_float(ma[k] & 0xffff0000u);
                acc = fmaf(fmaxf(lo, 0.0f), w2v[2 * k],     acc);
                acc = fmaf(fmaxf(hi, 0.0f), w2v[2 * k + 1], acc);
            }
        }
        // butterfly reduce within 16-lane group
        #pragma unroll
        for (int off = 1; off < 16; off <<= 1)
            acc += __shfl_xor(acc, off, 64);
        res[i] = acc;
    }

    if (L == 0) {
        float bb = b2[0];
        *(float4*)(out + e0 + g * 4) =
            make_float4(res[0] + bb, res[1] + bb, res[2] + bb, res[3] + bb);
    }
}

extern "C" void kernel_launch(void* const* d_in, const int* in_sizes, int n_in,
                              void* d_out, int out_size, void* d_ws, size_t ws_size,
                              hipStream_t stream) {
    const float* userf  = (const float*)d_in[0];
    const float* movief = (const float*)d_in[1];
    const int*   eidx   = (const int*)d_in[2];
    const float* W1     = (const float*)d_in[3];
    const float* b1     = (const float*)d_in[4];
    const float* W2     = (const float*)d_in[5];
    const float* b2     = (const float*)d_in[6];
    float* out = (float*)d_out;

    const int NU = in_sizes[0] / 128;   // 100000
    const int NM = in_sizes[1] / 128;   // 100000
    const int E  = in_sizes[2] / 2;     // 1000000

    uint4* Pu = (uint4*)d_ws;
    uint4* Pm = Pu + (size_t)NU * 16;   // 25.6 MB each

    proj_kernel<<<512, 256, 0, stream>>>(userf,  W1, nullptr, 0,   Pu, NU / 16);
    proj_kernel<<<512, 256, 0, stream>>>(movief, W1, b1,      128, Pm, NM / 16);
    edge_kernel<<<E / 64, 256, 0, stream>>>(eidx, eidx + E, Pu, Pm, W2, b2, out);
}

// Round 3
// 224.148 us; speedup vs baseline: 1.1659x; 1.1659x over previous
//
#include <hip/hip_runtime.h>
#include <hip/hip_bf16.h>

typedef short s8v __attribute__((ext_vector_type(8)));   // 8 bf16 (4 VGPRs) MFMA A/B frag
typedef float f4v __attribute__((ext_vector_type(4)));   // 4 fp32 MFMA C/D frag

__device__ __forceinline__ unsigned int bfround(float f) {
    unsigned int x = __float_as_uint(f);
    return (x + 0x7fffu + ((x >> 16) & 1u)) >> 16;  // RNE fp32->bf16
}
__device__ __forceinline__ unsigned int pack2f(float lo, float hi) {
    return bfround(lo) | (bfround(hi) << 16);
}

// Fused projection, both halves in one launch: even blocks -> users, odd -> movies.
// P[row][perm-col] (bf16) = feat[N,128] @ W1[whalf:,:] (+ bias for movie half).
// Column permutation perm(t*16+m) = m*8+t; edge kernel indexes W2 identically.
// One wave = one 16-row tile, all 128 output cols; no LDS, no barriers.
__global__ __launch_bounds__(256) void proj_kernel(
    const float* __restrict__ userf, const float* __restrict__ movief,
    const float* __restrict__ W1, const float* __restrict__ b1,
    uint4* __restrict__ Pu, uint4* __restrict__ Pm, int ntiles)
{
    const int half = blockIdx.x & 1;
    const float* __restrict__ feat = half ? movief : userf;
    uint4* __restrict__ P = half ? Pm : Pu;
    const int whalf = half << 7;

    const int lane = threadIdx.x & 63;
    const int m    = lane & 15;      // A-row / B-col index within tile
    const int q    = lane >> 4;      // quad: selects 8-chunk of K

    // One-time B fragments for all 8 column tiles (W1 128KB, L2-hot).
    s8v  bfrag[8][4];
    float bias_v[8];
    #pragma unroll
    for (int t = 0; t < 8; ++t) {
        int col = t * 16 + m;
        bias_v[t] = half ? b1[col] : 0.0f;
        #pragma unroll
        for (int c = 0; c < 4; ++c) {
            s8v bf;
            #pragma unroll
            for (int j = 0; j < 8; ++j)
                bf[j] = (short)bfround(W1[(size_t)(whalf + c * 32 + q * 8 + j) * 128 + col]);
            bfrag[t][c] = bf;
        }
    }

    const int widh = (blockIdx.x >> 1) * 4 + (threadIdx.x >> 6);  // wave id within half
    const int nwh  = (gridDim.x >> 1) * 4;                        // waves per half

    for (int tile = widh; tile < ntiles; tile += nwh) {
        const float4* arow = (const float4*)feat + (size_t)tile * 512;  // 16 rows * 32 float4

        float4 a[4][2];
        #pragma unroll
        for (int c = 0; c < 4; ++c) {
            a[c][0] = arow[m * 32 + c * 8 + q * 2 + 0];
            a[c][1] = arow[m * 32 + c * 8 + q * 2 + 1];
        }

        f4v acc[8];
        #pragma unroll
        for (int t = 0; t < 8; ++t)
            acc[t] = (f4v){bias_v[t], bias_v[t], bias_v[t], bias_v[t]};

        #pragma unroll
        for (int c = 0; c < 4; ++c) {
            s8v af;
            af[0] = (short)bfround(a[c][0].x); af[1] = (short)bfround(a[c][0].y);
            af[2] = (short)bfround(a[c][0].z); af[3] = (short)bfround(a[c][0].w);
            af[4] = (short)bfround(a[c][1].x); af[5] = (short)bfround(a[c][1].y);
            af[6] = (short)bfround(a[c][1].z); af[7] = (short)bfround(a[c][1].w);
            #pragma unroll
            for (int t = 0; t < 8; ++t)
                acc[t] = __builtin_amdgcn_mfma_f32_16x16x32_bf16(af, bfrag[t][c], acc[t], 0, 0, 0);
        }

        // C/D layout: col = t*16+m, row = q*4+r  [m89/m91]. Perm store -> one uint4/r,
        // 4x256B contiguous segments per store instruction.
        #pragma unroll
        for (int r = 0; r < 4; ++r) {
            uint4 wv;
            wv.x = pack2f(acc[0][r], acc[1][r]);
            wv.y = pack2f(acc[2][r], acc[3][r]);
            wv.z = pack2f(acc[4][r], acc[5][r]);
            wv.w = pack2f(acc[6][r], acc[7][r]);
            int row = tile * 16 + q * 4 + r;
            P[(size_t)row * 16 + m] = wv;
        }
    }
}

// out[e] = relu(Pu[src[e]] + Pm[dst[e]]) . W2 + b2   (b1 folded into Pm; perm'd dims)
// 16 lanes/edge, 16 edges/wave. All 8 gathers issued before any reduction (MLP=8/lane);
// indices via uniform broadcast loads instead of shuffles.
__global__ __launch_bounds__(256) void edge_kernel(
    const int* __restrict__ src, const int* __restrict__ dst,
    const uint4* __restrict__ Pu, const uint4* __restrict__ Pm,
    const float* __restrict__ W2, const float* __restrict__ b2,
    float* __restrict__ out)
{
    const int lane = threadIdx.x & 63;
    const int L    = lane & 15;      // sub-lane within edge group
    const int g    = lane >> 4;      // edge group 0..3
    const int eg   = (blockIdx.x * 4 + (threadIdx.x >> 6)) * 16 + g * 4;

    // W2 at perm position L*8+j is original col j*16+L
    float w2v[8];
    #pragma unroll
    for (int j = 0; j < 8; ++j) w2v[j] = W2[j * 16 + L];

    int si[4], di[4];
    #pragma unroll
    for (int i = 0; i < 4; ++i) { si[i] = src[eg + i]; di[i] = dst[eg + i]; }

    uint4 pu[4], pm[4];
    #pragma unroll
    for (int i = 0; i < 4; ++i) {
        pu[i] = Pu[(size_t)si[i] * 16 + L];   // 16B/lane, full 256B row per 16-lane group
        pm[i] = Pm[(size_t)di[i] * 16 + L];
    }

    float res[4];
    #pragma unroll
    for (int i = 0; i < 4; ++i) {
        const unsigned int ua[4] = {pu[i].x, pu[i].y, pu[i].z, pu[i].w};
        const unsigned int ma[4] = {pm[i].x, pm[i].y, pm[i].z, pm[i].w};
        float acc = 0.0f;
        #pragma unroll
        for (int k = 0; k < 4; ++k) {
            float lo = __uint_as_float(ua[k] << 16)         + __uint_as_float(ma[k] << 16);
            float hi = __uint_as_float(ua[k] & 0xffff0000u) + __uint_as_float(ma[k] & 0xffff0000u);
            acc = fmaf(fmaxf(lo, 0.0f), w2v[2 * k],     acc);
            acc = fmaf(fmaxf(hi, 0.0f), w2v[2 * k + 1], acc);
        }
        #pragma unroll
        for (int off = 1; off < 16; off <<= 1)
            acc += __shfl_xor(acc, off, 64);
        res[i] = acc;
    }

    if (L == 0) {
        float bb = b2[0];
        *(float4*)(out + eg) = make_float4(res[0] + bb, res[1] + bb, res[2] + bb, res[3] + bb);
    }
}

extern "C" void kernel_launch(void* const* d_in, const int* in_sizes, int n_in,
                              void* d_out, int out_size, void* d_ws, size_t ws_size,
                              hipStream_t stream) {
    const float* userf  = (const float*)d_in[0];
    const float* movief = (const float*)d_in[1];
    const int*   eidx   = (const int*)d_in[2];
    const float* W1     = (const float*)d_in[3];
    const float* b1     = (const float*)d_in[4];
    const float* W2     = (const float*)d_in[5];
    const float* b2     = (const float*)d_in[6];
    float* out = (float*)d_out;

    const int NU = in_sizes[0] / 128;   // 100000
    const int NM = in_sizes[1] / 128;   // 100000
    const int E  = in_sizes[2] / 2;     // 1000000

    uint4* Pu = (uint4*)d_ws;
    uint4* Pm = Pu + (size_t)NU * 16;   // 25.6 MB each

    proj_kernel<<<512, 256, 0, stream>>>(userf, movief, W1, b1, Pu, Pm, NU / 16);
    edge_kernel<<<E / 64, 256, 0, stream>>>(eidx, eidx + E, Pu, Pm, W2, b2, out);
}

// Round 4
// 223.847 us; speedup vs baseline: 1.1675x; 1.0013x over previous
//
#include <hip/hip_runtime.h>
#include <hip/hip_bf16.h>

typedef short s8v __attribute__((ext_vector_type(8)));   // 8 bf16 (4 VGPRs) MFMA A/B frag
typedef float f4v __attribute__((ext_vector_type(4)));   // 4 fp32 MFMA C/D frag

__device__ __forceinline__ unsigned int bfround(float f) {
    unsigned int x = __float_as_uint(f);
    return (x + 0x7fffu + ((x >> 16) & 1u)) >> 16;  // RNE fp32->bf16
}
__device__ __forceinline__ unsigned int pack2f(float lo, float hi) {
    return bfround(lo) | (bfround(hi) << 16);
}

// Fused projection, both halves in one launch: even blocks -> users, odd -> movies.
// P[row][perm-col] (bf16) = feat[N,128] @ W1[whalf:,:] (+ bias for movie half).
// Column permutation perm(t*16+m) = m*8+t; edge kernel indexes W2 identically.
// One wave = one 16-row tile, all 128 output cols; no LDS, no barriers.
__global__ __launch_bounds__(256) void proj_kernel(
    const float* __restrict__ userf, const float* __restrict__ movief,
    const float* __restrict__ W1, const float* __restrict__ b1,
    uint4* __restrict__ Pu, uint4* __restrict__ Pm, int ntiles)
{
    const int half = blockIdx.x & 1;
    const float* __restrict__ feat = half ? movief : userf;
    uint4* __restrict__ P = half ? Pm : Pu;
    const int whalf = half << 7;

    const int lane = threadIdx.x & 63;
    const int m    = lane & 15;      // A-row / B-col index within tile
    const int q    = lane >> 4;      // quad: selects 8-chunk of K

    // One-time B fragments for all 8 column tiles (W1 128KB, L2-hot).
    s8v  bfrag[8][4];
    float bias_v[8];
    #pragma unroll
    for (int t = 0; t < 8; ++t) {
        int col = t * 16 + m;
        bias_v[t] = half ? b1[col] : 0.0f;
        #pragma unroll
        for (int c = 0; c < 4; ++c) {
            s8v bf;
            #pragma unroll
            for (int j = 0; j < 8; ++j)
                bf[j] = (short)bfround(W1[(size_t)(whalf + c * 32 + q * 8 + j) * 128 + col]);
            bfrag[t][c] = bf;
        }
    }

    const int widh = (blockIdx.x >> 1) * 4 + (threadIdx.x >> 6);  // wave id within half
    const int nwh  = (gridDim.x >> 1) * 4;                        // waves per half

    for (int tile = widh; tile < ntiles; tile += nwh) {
        const float4* arow = (const float4*)feat + (size_t)tile * 512;  // 16 rows * 32 float4

        float4 a[4][2];
        #pragma unroll
        for (int c = 0; c < 4; ++c) {
            a[c][0] = arow[m * 32 + c * 8 + q * 2 + 0];
            a[c][1] = arow[m * 32 + c * 8 + q * 2 + 1];
        }

        f4v acc[8];
        #pragma unroll
        for (int t = 0; t < 8; ++t)
            acc[t] = (f4v){bias_v[t], bias_v[t], bias_v[t], bias_v[t]};

        #pragma unroll
        for (int c = 0; c < 4; ++c) {
            s8v af;
            af[0] = (short)bfround(a[c][0].x); af[1] = (short)bfround(a[c][0].y);
            af[2] = (short)bfround(a[c][0].z); af[3] = (short)bfround(a[c][0].w);
            af[4] = (short)bfround(a[c][1].x); af[5] = (short)bfround(a[c][1].y);
            af[6] = (short)bfround(a[c][1].z); af[7] = (short)bfround(a[c][1].w);
            #pragma unroll
            for (int t = 0; t < 8; ++t)
                acc[t] = __builtin_amdgcn_mfma_f32_16x16x32_bf16(af, bfrag[t][c], acc[t], 0, 0, 0);
        }

        // C/D layout: col = t*16+m, row = q*4+r  [m89/m91]. Perm store -> one uint4/r,
        // 4x256B contiguous segments per store instruction.
        #pragma unroll
        for (int r = 0; r < 4; ++r) {
            uint4 wv;
            wv.x = pack2f(acc[0][r], acc[1][r]);
            wv.y = pack2f(acc[2][r], acc[3][r]);
            wv.z = pack2f(acc[4][r], acc[5][r]);
            wv.w = pack2f(acc[6][r], acc[7][r]);
            int row = tile * 16 + q * 4 + r;
            P[(size_t)row * 16 + m] = wv;
        }
    }
}

// out[e] = relu(Pu[src[e]] + Pm[dst[e]]) . W2 + b2   (b1 folded into Pm; perm'd dims)
// 16 lanes/edge, 32 edges/wave: 16 uint4 gathers in flight per lane before any math.
__global__ __launch_bounds__(256, 4) void edge_kernel(
    const int* __restrict__ src, const int* __restrict__ dst,
    const uint4* __restrict__ Pu, const uint4* __restrict__ Pm,
    const float* __restrict__ W2, const float* __restrict__ b2,
    float* __restrict__ out, int E)
{
    const int lane = threadIdx.x & 63;
    const int L    = lane & 15;      // sub-lane within edge group
    const int g    = lane >> 4;      // edge group 0..3
    const int e0   = (blockIdx.x * 4 + (threadIdx.x >> 6)) * 32;  // wave's 32 edges
    if (e0 >= E) return;
    const int eb   = e0 + g * 8;     // this group's 8 edges

    // W2 at perm position L*8+j is original col j*16+L
    float w2v[8];
    #pragma unroll
    for (int j = 0; j < 8; ++j) w2v[j] = W2[j * 16 + L];

    int si[8], di[8];
    #pragma unroll
    for (int i = 0; i < 8; ++i) { si[i] = src[eb + i]; di[i] = dst[eb + i]; }

    // All 16 gathers issued before any consumption (MLP=16/lane).
    uint4 pu[8], pm[8];
    #pragma unroll
    for (int i = 0; i < 8; ++i) {
        pu[i] = Pu[(size_t)si[i] * 16 + L];   // 16B/lane, full 256B row per 16-lane group
        pm[i] = Pm[(size_t)di[i] * 16 + L];
    }

    float res[8];
    #pragma unroll
    for (int i = 0; i < 8; ++i) {
        const unsigned int ua[4] = {pu[i].x, pu[i].y, pu[i].z, pu[i].w};
        const unsigned int ma[4] = {pm[i].x, pm[i].y, pm[i].z, pm[i].w};
        float acc = 0.0f;
        #pragma unroll
        for (int k = 0; k < 4; ++k) {
            float lo = __uint_as_float(ua[k] << 16)         + __uint_as_float(ma[k] << 16);
            float hi = __uint_as_float(ua[k] & 0xffff0000u) + __uint_as_float(ma[k] & 0xffff0000u);
            acc = fmaf(fmaxf(lo, 0.0f), w2v[2 * k],     acc);
            acc = fmaf(fmaxf(hi, 0.0f), w2v[2 * k + 1], acc);
        }
        #pragma unroll
        for (int off = 1; off < 16; off <<= 1)
            acc += __shfl_xor(acc, off, 64);
        res[i] = acc;
    }

    if (L == 0) {
        float bb = b2[0];
        *(float4*)(out + eb)     = make_float4(res[0] + bb, res[1] + bb, res[2] + bb, res[3] + bb);
        *(float4*)(out + eb + 4) = make_float4(res[4] + bb, res[5] + bb, res[6] + bb, res[7] + bb);
    }
}

extern "C" void kernel_launch(void* const* d_in, const int* in_sizes, int n_in,
                              void* d_out, int out_size, void* d_ws, size_t ws_size,
                              hipStream_t stream) {
    const float* userf  = (const float*)d_in[0];
    const float* movief = (const float*)d_in[1];
    const int*   eidx   = (const int*)d_in[2];
    const float* W1     = (const float*)d_in[3];
    const float* b1     = (const float*)d_in[4];
    const float* W2     = (const float*)d_in[5];
    const float* b2     = (const float*)d_in[6];
    float* out = (float*)d_out;

    const int NU = in_sizes[0] / 128;   // 100000
    const int NM = in_sizes[1] / 128;   // 100000
    const int E  = in_sizes[2] / 2;     // 1000000

    uint4* Pu = (uint4*)d_ws;
    uint4* Pm = Pu + (size_t)NU * 16;   // 25.6 MB each

    proj_kernel<<<512, 256, 0, stream>>>(userf, movief, W1, b1, Pu, Pm, NU / 16);
    edge_kernel<<<(E + 127) / 128, 256, 0, stream>>>(eidx, eidx + E, Pu, Pm, W2, b2, out, E);
}

// Round 5
// 200.783 us; speedup vs baseline: 1.3016x; 1.1149x over previous
//
#include <hip/hip_runtime.h>
#include <hip/hip_bf16.h>

typedef short s8v __attribute__((ext_vector_type(8)));   // 8 bf16 (4 VGPRs) MFMA A/B frag
typedef float f4v __attribute__((ext_vector_type(4)));   // 4 fp32 MFMA C/D frag

__device__ __forceinline__ unsigned int bfround(float f) {
    unsigned int x = __float_as_uint(f);
    return (x + 0x7fffu + ((x >> 16) & 1u)) >> 16;  // RNE fp32->bf16
}

// signed-int8 extract byte k of word w -> float  (v_bfe_i32 + v_cvt_f32_i32)
__device__ __forceinline__ float i8f(unsigned int w, int k) {
    return (float)((int)(signed char)(w >> (8 * k)));
}

// Fused projection: even blocks -> users, odd -> movies.
// P rows stored as int8 (128B) with column permutation perm(t*16+m)=m*8+t,
// plus per-row fp32 scale:  p_col = q_col * scale[row].
__global__ __launch_bounds__(256) void proj_kernel(
    const float* __restrict__ userf, const float* __restrict__ movief,
    const float* __restrict__ W1, const float* __restrict__ b1,
    uint2* __restrict__ Pu, uint2* __restrict__ Pm,
    float* __restrict__ SU, float* __restrict__ SM, int ntiles)
{
    const int half = blockIdx.x & 1;
    const float* __restrict__ feat = half ? movief : userf;
    uint2* __restrict__ P = half ? Pm : Pu;
    float* __restrict__ S = half ? SM : SU;
    const int whalf = half << 7;

    const int lane = threadIdx.x & 63;
    const int m    = lane & 15;      // A-row / B-col index within tile
    const int q    = lane >> 4;      // quad: selects 8-chunk of K

    // One-time B fragments for all 8 column tiles (W1 128KB, L2-hot).
    s8v  bfrag[8][4];
    float bias_v[8];
    #pragma unroll
    for (int t = 0; t < 8; ++t) {
        int col = t * 16 + m;
        bias_v[t] = half ? b1[col] : 0.0f;
        #pragma unroll
        for (int c = 0; c < 4; ++c) {
            s8v bf;
            #pragma unroll
            for (int j = 0; j < 8; ++j)
                bf[j] = (short)bfround(W1[(size_t)(whalf + c * 32 + q * 8 + j) * 128 + col]);
            bfrag[t][c] = bf;
        }
    }

    const int widh = (blockIdx.x >> 1) * 4 + (threadIdx.x >> 6);  // wave id within half
    const int nwh  = (gridDim.x >> 1) * 4;                        // waves per half

    for (int tile = widh; tile < ntiles; tile += nwh) {
        const float4* arow = (const float4*)feat + (size_t)tile * 512;  // 16 rows * 32 float4

        float4 a[4][2];
        #pragma unroll
        for (int c = 0; c < 4; ++c) {
            a[c][0] = arow[m * 32 + c * 8 + q * 2 + 0];
            a[c][1] = arow[m * 32 + c * 8 + q * 2 + 1];
        }

        f4v acc[8];
        #pragma unroll
        for (int t = 0; t < 8; ++t)
            acc[t] = (f4v){bias_v[t], bias_v[t], bias_v[t], bias_v[t]};

        #pragma unroll
        for (int c = 0; c < 4; ++c) {
            s8v af;
            af[0] = (short)bfround(a[c][0].x); af[1] = (short)bfround(a[c][0].y);
            af[2] = (short)bfround(a[c][0].z); af[3] = (short)bfround(a[c][0].w);
            af[4] = (short)bfround(a[c][1].x); af[5] = (short)bfround(a[c][1].y);
            af[6] = (short)bfround(a[c][1].z); af[7] = (short)bfround(a[c][1].w);
            #pragma unroll
            for (int t = 0; t < 8; ++t)
                acc[t] = __builtin_amdgcn_mfma_f32_16x16x32_bf16(af, bfrag[t][c], acc[t], 0, 0, 0);
        }

        // C/D layout: col = t*16+m, row = q*4+r  [m89/m91 verified].
        // Row (q*4+r) spans the 16 m-lanes of this q-group x 8 t-regs -> cross-lane
        // absmax within the 16-lane group (xor offsets 1..8 stay inside it).
        #pragma unroll
        for (int r = 0; r < 4; ++r) {
            float mx = 0.0f;
            #pragma unroll
            for (int t = 0; t < 8; ++t) mx = fmaxf(mx, fabsf(acc[t][r]));
            #pragma unroll
            for (int off = 1; off < 16; off <<= 1)
                mx = fmaxf(mx, __shfl_xor(mx, off, 64));
            float inv = mx > 0.0f ? 127.0f / mx : 0.0f;

            unsigned int lo = 0, hi = 0;
            #pragma unroll
            for (int t = 0; t < 4; ++t) {
                lo |= ((unsigned int)(__float2int_rn(acc[t][r]     * inv) & 0xff)) << (8 * t);
                hi |= ((unsigned int)(__float2int_rn(acc[t + 4][r] * inv) & 0xff)) << (8 * t);
            }
            int row = tile * 16 + q * 4 + r;
            P[(size_t)row * 16 + m] = make_uint2(lo, hi);  // 16 lanes x 8B = one 128B row
            if (m == 0) S[row] = mx * (1.0f / 127.0f);
        }
    }
}

// out[e] = relu(su*Qu[src] + sm*Qm[dst]) . W2 + b2   (b1 folded into Pm; perm'd dims)
// 16 lanes/edge (uint2 = 8 int8 dims per lane), 16 edges/wave.
__global__ __launch_bounds__(256) void edge_kernel(
    const int* __restrict__ src, const int* __restrict__ dst,
    const uint2* __restrict__ Pu, const uint2* __restrict__ Pm,
    const float* __restrict__ SU, const float* __restrict__ SM,
    const float* __restrict__ W2, const float* __restrict__ b2,
    float* __restrict__ out)
{
    const int lane = threadIdx.x & 63;
    const int L    = lane & 15;      // sub-lane within edge group
    const int g    = lane >> 4;      // edge group 0..3
    const int eg   = (blockIdx.x * 4 + (threadIdx.x >> 6)) * 16 + g * 4;

    // W2 at perm position L*8+j is original col j*16+L
    float w2v[8];
    #pragma unroll
    for (int j = 0; j < 8; ++j) w2v[j] = W2[j * 16 + L];

    int si[4], di[4];
    #pragma unroll
    for (int i = 0; i < 4; ++i) { si[i] = src[eg + i]; di[i] = dst[eg + i]; }

    // All gathers + scales issued before any consumption.
    uint2 pu[4], pm[4];
    float scu[4], scm[4];
    #pragma unroll
    for (int i = 0; i < 4; ++i) {
        pu[i] = Pu[(size_t)si[i] * 16 + L];   // 8B/lane, one 128B line per 16-lane group
        pm[i] = Pm[(size_t)di[i] * 16 + L];
        scu[i] = SU[si[i]];                   // 400KB arrays, L2-resident
        scm[i] = SM[di[i]];
    }

    float res[4];
    #pragma unroll
    for (int i = 0; i < 4; ++i) {
        const unsigned int uw[2] = {pu[i].x, pu[i].y};
        const unsigned int mw[2] = {pm[i].x, pm[i].y};
        float acc = 0.0f;
        #pragma unroll
        for (int v = 0; v < 2; ++v) {
            #pragma unroll
            for (int k = 0; k < 4; ++k) {
                float h = fmaf(scu[i], i8f(uw[v], k), scm[i] * i8f(mw[v], k));
                acc = fmaf(fmaxf(h, 0.0f), w2v[v * 4 + k], acc);
            }
        }
        #pragma unroll
        for (int off = 1; off < 16; off <<= 1)
            acc += __shfl_xor(acc, off, 64);
        res[i] = acc;
    }

    if (L == 0) {
        float bb = b2[0];
        *(float4*)(out + eg) = make_float4(res[0] + bb, res[1] + bb, res[2] + bb, res[3] + bb);
    }
}

extern "C" void kernel_launch(void* const* d_in, const int* in_sizes, int n_in,
                              void* d_out, int out_size, void* d_ws, size_t ws_size,
                              hipStream_t stream) {
    const float* userf  = (const float*)d_in[0];
    const float* movief = (const float*)d_in[1];
    const int*   eidx   = (const int*)d_in[2];
    const float* W1     = (const float*)d_in[3];
    const float* b1     = (const float*)d_in[4];
    const float* W2     = (const float*)d_in[5];
    const float* b2     = (const float*)d_in[6];
    float* out = (float*)d_out;

    const int NU = in_sizes[0] / 128;   // 100000
    const int NM = in_sizes[1] / 128;   // 100000
    const int E  = in_sizes[2] / 2;     // 1000000

    // Workspace: Qu 12.8MB | Qm 12.8MB | SU 400KB | SM 400KB
    uint2* Pu = (uint2*)d_ws;
    uint2* Pm = Pu + (size_t)NU * 16;
    float* SU = (float*)(Pm + (size_t)NM * 16);
    float* SM = SU + NU;

    proj_kernel<<<512, 256, 0, stream>>>(userf, movief, W1, b1, Pu, Pm, SU, SM, NU / 16);
    edge_kernel<<<E / 64, 256, 0, stream>>>(eidx, eidx + E, Pu, Pm, SU, SM, W2, b2, out);
}

// Round 6
// 192.861 us; speedup vs baseline: 1.3551x; 1.0411x over previous
//
#include <hip/hip_runtime.h>
#include <hip/hip_bf16.h>

typedef short s8v __attribute__((ext_vector_type(8)));   // 8 bf16 (4 VGPRs) MFMA A/B frag
typedef float f4v __attribute__((ext_vector_type(4)));   // 4 fp32 MFMA C/D frag

__device__ __forceinline__ unsigned int bfround(float f) {
    unsigned int x = __float_as_uint(f);
    return (x + 0x7fffu + ((x >> 16) & 1u)) >> 16;  // RNE fp32->bf16
}

// signed-int8 extract byte k of word w -> float  (v_bfe_i32 + v_cvt_f32_i32)
__device__ __forceinline__ float i8f(unsigned int w, int k) {
    return (float)((int)(signed char)(w >> (8 * k)));
}

// Pack W1 (fp32, [256x128]) into bf16 MFMA B-fragments laid out per-lane so proj
// waves read them with fully-coalesced uint4 loads.
// WF[half][c][t][lane] : uint4 = 8 bf16, j=0..7, k = c*32 + (lane>>4)*8 + j, col = t*16 + (lane&15)
__global__ __launch_bounds__(256) void pack_w(const float* __restrict__ W1,
                                              uint4* __restrict__ WF)
{
    const int half = blockIdx.x;
    #pragma unroll
    for (int iter = 0; iter < 8; ++iter) {
        int idx  = iter * 256 + threadIdx.x;   // (c,t,lane) flattened: idx = ((c*8)+t)*64+lane
        int lane = idx & 63;
        int t    = (idx >> 6) & 7;
        int c    = idx >> 9;
        int q = lane >> 4, m = lane & 15;
        unsigned int w[4];
        #pragma unroll
        for (int jj = 0; jj < 4; ++jj) {
            float lo = W1[(size_t)(half * 128 + c * 32 + q * 8 + 2 * jj    ) * 128 + t * 16 + m];
            float hi = W1[(size_t)(half * 128 + c * 32 + q * 8 + 2 * jj + 1) * 128 + t * 16 + m];
            w[jj] = bfround(lo) | (bfround(hi) << 16);
        }
        WF[(size_t)half * 2048 + idx] = make_uint4(w[0], w[1], w[2], w[3]);
    }
}

// Projection: one wave = one 16-row tile, all 128 perm'd cols. Even blocks->users,
// odd->movies. int8 rows + per-row fp32 scale. Perm(t*16+m) = m*8+t.
__global__ __launch_bounds__(256, 3) void proj_kernel(
    const float* __restrict__ userf, const float* __restrict__ movief,
    const uint4* __restrict__ WF, const float* __restrict__ b1,
    uint2* __restrict__ Pu, uint2* __restrict__ Pm,
    float* __restrict__ SU, float* __restrict__ SM, int ntiles)
{
    const int half = blockIdx.x & 1;
    const int tile = (blockIdx.x >> 1) * 4 + (threadIdx.x >> 6);
    if (tile >= ntiles) return;
    const float* __restrict__ feat = half ? movief : userf;
    uint2* __restrict__ P = half ? Pm : Pu;
    float* __restrict__ S = half ? SM : SU;

    const int lane = threadIdx.x & 63;
    const int m    = lane & 15;
    const int q    = lane >> 4;

    // A loads first (HBM, longest latency): 16 rows x 128 cols fp32, 128B/lane.
    const float4* arow = (const float4*)feat + (size_t)tile * 512;
    float4 a[4][2];
    #pragma unroll
    for (int c = 0; c < 4; ++c) {
        a[c][0] = arow[m * 32 + c * 8 + q * 2 + 0];
        a[c][1] = arow[m * 32 + c * 8 + q * 2 + 1];
    }

    float bias_v[8];
    #pragma unroll
    for (int t = 0; t < 8; ++t)
        bias_v[t] = half ? b1[t * 16 + m] : 0.0f;

    f4v acc[8];
    #pragma unroll
    for (int t = 0; t < 8; ++t)
        acc[t] = (f4v){bias_v[t], bias_v[t], bias_v[t], bias_v[t]};

    // W fragments: 32 coalesced uint4 loads from the 64KB packed table (L2-hot).
    const uint4* wf = WF + (size_t)half * 2048;
    #pragma unroll
    for (int c = 0; c < 4; ++c) {
        uint4 fr[8];
        #pragma unroll
        for (int t = 0; t < 8; ++t)
            fr[t] = wf[(c * 8 + t) * 64 + lane];

        s8v af;
        af[0] = (short)bfround(a[c][0].x); af[1] = (short)bfround(a[c][0].y);
        af[2] = (short)bfround(a[c][0].z); af[3] = (short)bfround(a[c][0].w);
        af[4] = (short)bfround(a[c][1].x); af[5] = (short)bfround(a[c][1].y);
        af[6] = (short)bfround(a[c][1].z); af[7] = (short)bfround(a[c][1].w);

        #pragma unroll
        for (int t = 0; t < 8; ++t)
            acc[t] = __builtin_amdgcn_mfma_f32_16x16x32_bf16(af, *(const s8v*)&fr[t], acc[t], 0, 0, 0);
    }

    // C/D layout: col = t*16+m, row = q*4+r  [m89/m91 verified]. Quantize each row
    // to int8 with cross-lane absmax over the 16-lane m-group (xor 1..8 stays inside).
    #pragma unroll
    for (int r = 0; r < 4; ++r) {
        float mx = 0.0f;
        #pragma unroll
        for (int t = 0; t < 8; ++t) mx = fmaxf(mx, fabsf(acc[t][r]));
        #pragma unroll
        for (int off = 1; off < 16; off <<= 1)
            mx = fmaxf(mx, __shfl_xor(mx, off, 64));
        float inv = mx > 0.0f ? 127.0f / mx : 0.0f;

        unsigned int lo = 0, hi = 0;
        #pragma unroll
        for (int t = 0; t < 4; ++t) {
            lo |= ((unsigned int)(__float2int_rn(acc[t][r]     * inv) & 0xff)) << (8 * t);
            hi |= ((unsigned int)(__float2int_rn(acc[t + 4][r] * inv) & 0xff)) << (8 * t);
        }
        int row = tile * 16 + q * 4 + r;
        P[(size_t)row * 16 + m] = make_uint2(lo, hi);  // 16 lanes x 8B = one 128B row
        if (m == 0) S[row] = mx * (1.0f / 127.0f);
    }
}

// out[e] = relu(su*Qu[src] + sm*Qm[dst]) . W2 + b2   (b1 folded into Pm; perm'd dims)
// 16 lanes/edge (uint2 = 8 int8 dims per lane), 16 edges/wave.
__global__ __launch_bounds__(256) void edge_kernel(
    const int* __restrict__ src, const int* __restrict__ dst,
    const uint2* __restrict__ Pu, const uint2* __restrict__ Pm,
    const float* __restrict__ SU, const float* __restrict__ SM,
    const float* __restrict__ W2, const float* __restrict__ b2,
    float* __restrict__ out)
{
    const int lane = threadIdx.x & 63;
    const int L    = lane & 15;      // sub-lane within edge group
    const int g    = lane >> 4;      // edge group 0..3
    const int eg   = (blockIdx.x * 4 + (threadIdx.x >> 6)) * 16 + g * 4;

    // W2 at perm position L*8+j is original col j*16+L
    float w2v[8];
    #pragma unroll
    for (int j = 0; j < 8; ++j) w2v[j] = W2[j * 16 + L];

    int si[4], di[4];
    #pragma unroll
    for (int i = 0; i < 4; ++i) { si[i] = src[eg + i]; di[i] = dst[eg + i]; }

    uint2 pu[4], pm[4];
    float scu[4], scm[4];
    #pragma unroll
    for (int i = 0; i < 4; ++i) {
        pu[i] = Pu[(size_t)si[i] * 16 + L];   // 8B/lane, one 128B line per 16-lane group
        pm[i] = Pm[(size_t)di[i] * 16 + L];
        scu[i] = SU[si[i]];                   // 400KB arrays, L2-resident
        scm[i] = SM[di[i]];
    }

    float res[4];
    #pragma unroll
    for (int i = 0; i < 4; ++i) {
        const unsigned int uw[2] = {pu[i].x, pu[i].y};
        const unsigned int mw[2] = {pm[i].x, pm[i].y};
        float acc = 0.0f;
        #pragma unroll
        for (int v = 0; v < 2; ++v) {
            #pragma unroll
            for (int k = 0; k < 4; ++k) {
                float h = fmaf(scu[i], i8f(uw[v], k), scm[i] * i8f(mw[v], k));
                acc = fmaf(fmaxf(h, 0.0f), w2v[v * 4 + k], acc);
            }
        }
        #pragma unroll
        for (int off = 1; off < 16; off <<= 1)
            acc += __shfl_xor(acc, off, 64);
        res[i] = acc;
    }

    if (L == 0) {
        float bb = b2[0];
        *(float4*)(out + eg) = make_float4(res[0] + bb, res[1] + bb, res[2] + bb, res[3] + bb);
    }
}

extern "C" void kernel_launch(void* const* d_in, const int* in_sizes, int n_in,
                              void* d_out, int out_size, void* d_ws, size_t ws_size,
                              hipStream_t stream) {
    const float* userf  = (const float*)d_in[0];
    const float* movief = (const float*)d_in[1];
    const int*   eidx   = (const int*)d_in[2];
    const float* W1     = (const float*)d_in[3];
    const float* b1     = (const float*)d_in[4];
    const float* W2     = (const float*)d_in[5];
    const float* b2     = (const float*)d_in[6];
    float* out = (float*)d_out;

    const int NU = in_sizes[0] / 128;   // 100000
    const int NM = in_sizes[1] / 128;   // 100000
    const int E  = in_sizes[2] / 2;     // 1000000

    // Workspace: Qu 12.8MB | Qm 12.8MB | SU 400KB | SM 400KB | WF 64KB
    uint2* Pu = (uint2*)d_ws;
    uint2* Pm = Pu + (size_t)NU * 16;
    float* SU = (float*)(Pm + (size_t)NM * 16);
    float* SM = SU + NU;
    uint4* WF = (uint4*)(SM + NM);

    const int ntiles = NU / 16;                       // 6250 per half
    const int nblk   = 2 * ((ntiles + 3) / 4);        // 3126

    pack_w<<<2, 256, 0, stream>>>(W1, WF);
    proj_kernel<<<nblk, 256, 0, stream>>>(userf, movief, WF, b1, Pu, Pm, SU, SM, ntiles);
    edge_kernel<<<E / 64, 256, 0, stream>>>(eidx, eidx + E, Pu, Pm, SU, SM, W2, b2, out);
}

// Round 7
// 192.316 us; speedup vs baseline: 1.3589x; 1.0028x over previous
//
#include <hip/hip_runtime.h>
#include <hip/hip_bf16.h>

typedef short s8v __attribute__((ext_vector_type(8)));   // 8 bf16 (4 VGPRs) MFMA A/B frag
typedef float f4v __attribute__((ext_vector_type(4)));   // 4 fp32 MFMA C/D frag

__device__ __forceinline__ unsigned int bfround(float f) {
    unsigned int x = __float_as_uint(f);
    return (x + 0x7fffu + ((x >> 16) & 1u)) >> 16;  // RNE fp32->bf16
}
// packed RNE fp32x2 -> bf16x2 (v_cvt_pk_bf16_f32 on gfx950)
__device__ __forceinline__ unsigned int pkbf(float x, float y) {
    __hip_bfloat162 h = __float22bfloat162_rn(make_float2(x, y));
    return *(unsigned int*)&h;
}
// signed-int8 extract byte k of word w -> float  (v_bfe_i32 + v_cvt_f32_i32)
__device__ __forceinline__ float i8f(unsigned int w, int k) {
    return (float)((int)(signed char)(w >> (8 * k)));
}

// Pack W1 (fp32, [256x128]) into bf16 MFMA B-fragments laid out per-lane so proj
// waves read them with fully-coalesced uint4 loads.
// WF[half][c][t][lane] : uint4 = 8 bf16, j=0..7, k = c*32 + (lane>>4)*8 + j, col = t*16 + (lane&15)
__global__ __launch_bounds__(256) void pack_w(const float* __restrict__ W1,
                                              uint4* __restrict__ WF)
{
    const int half = blockIdx.x;
    #pragma unroll
    for (int iter = 0; iter < 8; ++iter) {
        int idx  = iter * 256 + threadIdx.x;   // (c,t,lane) flattened
        int lane = idx & 63;
        int t    = (idx >> 6) & 7;
        int c    = idx >> 9;
        int q = lane >> 4, m = lane & 15;
        unsigned int w[4];
        #pragma unroll
        for (int jj = 0; jj < 4; ++jj) {
            float lo = W1[(size_t)(half * 128 + c * 32 + q * 8 + 2 * jj    ) * 128 + t * 16 + m];
            float hi = W1[(size_t)(half * 128 + c * 32 + q * 8 + 2 * jj + 1) * 128 + t * 16 + m];
            w[jj] = bfround(lo) | (bfround(hi) << 16);
        }
        WF[(size_t)half * 2048 + idx] = make_uint4(w[0], w[1], w[2], w[3]);
    }
}

// Projection v3: persistent waves, software-pipelined A prefetch, contiguous half
// split (blocks [0,bph) users / [bph,2*bph) movies -> per-CU L1 keeps one WF half).
// int8 rows + per-row fp32 scale, column perm(t*16+m) = m*8+t.
__global__ __launch_bounds__(256) void proj_kernel(
    const float* __restrict__ userf, const float* __restrict__ movief,
    const uint4* __restrict__ WF, const float* __restrict__ b1,
    uint2* __restrict__ Pu, uint2* __restrict__ Pm,
    float* __restrict__ SU, float* __restrict__ SM,
    int ntiles, int bph)
{
    const int half = blockIdx.x >= bph;
    const int bid  = half ? blockIdx.x - bph : blockIdx.x;
    const float* __restrict__ feat = half ? movief : userf;
    uint2* __restrict__ P = half ? Pm : Pu;
    float* __restrict__ S = half ? SM : SU;
    const uint4* __restrict__ wf = WF + (size_t)half * 2048;

    const int lane = threadIdx.x & 63;
    const int m    = lane & 15;
    const int q    = lane >> 4;

    float bias_v[8];
    #pragma unroll
    for (int t = 0; t < 8; ++t)
        bias_v[t] = half ? b1[t * 16 + m] : 0.0f;

    const int wid = bid * 4 + (threadIdx.x >> 6);   // wave id within half
    const int nw  = bph * 4;                        // waves per half

#define LOAD_A(dst, t_) do {                                          \
        const float4* arow_ = (const float4*)feat + (size_t)(t_) * 512; \
        _Pragma("unroll")                                             \
        for (int c_ = 0; c_ < 4; ++c_) {                              \
            dst[c_][0] = arow_[m * 32 + c_ * 8 + q * 2 + 0];          \
            dst[c_][1] = arow_[m * 32 + c_ * 8 + q * 2 + 1];          \
        }                                                             \
    } while (0)

    float4 a[4][2];
    int tile = wid;
    if (tile < ntiles) LOAD_A(a, tile);

    while (tile < ntiles) {
        const int nxt = tile + nw;
        float4 an[4][2];
        if (nxt < ntiles) LOAD_A(an, nxt);   // in flight across this tile's compute

        f4v acc[8];
        #pragma unroll
        for (int t = 0; t < 8; ++t)
            acc[t] = (f4v){bias_v[t], bias_v[t], bias_v[t], bias_v[t]};

        #pragma unroll
        for (int c = 0; c < 4; ++c) {
            uint4 fr[8];
            #pragma unroll
            for (int t = 0; t < 8; ++t)
                fr[t] = wf[(c * 8 + t) * 64 + lane];   // L1-hot (32KB table/CU)

            uint4 aw;
            aw.x = pkbf(a[c][0].x, a[c][0].y);
            aw.y = pkbf(a[c][0].z, a[c][0].w);
            aw.z = pkbf(a[c][1].x, a[c][1].y);
            aw.w = pkbf(a[c][1].z, a[c][1].w);
            s8v af = *(const s8v*)&aw;

            #pragma unroll
            for (int t = 0; t < 8; ++t)
                acc[t] = __builtin_amdgcn_mfma_f32_16x16x32_bf16(af, *(const s8v*)&fr[t], acc[t], 0, 0, 0);
        }

        // C/D layout: col = t*16+m, row = q*4+r  [m89/m91 verified]. int8-quantize
        // each row; absmax over the 16-lane m-group (xor 1..8 stays in-group).
        #pragma unroll
        for (int r = 0; r < 4; ++r) {
            float mx = 0.0f;
            #pragma unroll
            for (int t = 0; t < 8; ++t) mx = fmaxf(mx, fabsf(acc[t][r]));
            #pragma unroll
            for (int off = 1; off < 16; off <<= 1)
                mx = fmaxf(mx, __shfl_xor(mx, off, 64));
            float inv = mx > 0.0f ? 127.0f / mx : 0.0f;

            unsigned int lo = 0, hi = 0;
            #pragma unroll
            for (int t = 0; t < 4; ++t) {
                lo |= ((unsigned int)(__float2int_rn(acc[t][r]     * inv) & 0xff)) << (8 * t);
                hi |= ((unsigned int)(__float2int_rn(acc[t + 4][r] * inv) & 0xff)) << (8 * t);
            }
            int row = tile * 16 + q * 4 + r;
            P[(size_t)row * 16 + m] = make_uint2(lo, hi);  // 16 lanes x 8B = one 128B row
            if (m == 0) S[row] = mx * (1.0f / 127.0f);
        }

        #pragma unroll
        for (int c = 0; c < 4; ++c) {
            a[c][0] = an[c][0];
            a[c][1] = an[c][1];
        }
        tile = nxt;
    }
#undef LOAD_A
}

// out[e] = relu(su*Qu[src] + sm*Qm[dst]) . W2 + b2   (b1 folded into Pm; perm'd dims)
// 16 lanes/edge (uint2 = 8 int8 dims per lane), 16 edges/wave.
__global__ __launch_bounds__(256) void edge_kernel(
    const int* __restrict__ src, const int* __restrict__ dst,
    const uint2* __restrict__ Pu, const uint2* __restrict__ Pm,
    const float* __restrict__ SU, const float* __restrict__ SM,
    const float* __restrict__ W2, const float* __restrict__ b2,
    float* __restrict__ out)
{
    const int lane = threadIdx.x & 63;
    const int L    = lane & 15;      // sub-lane within edge group
    const int g    = lane >> 4;      // edge group 0..3
    const int eg   = (blockIdx.x * 4 + (threadIdx.x >> 6)) * 16 + g * 4;

    // W2 at perm position L*8+j is original col j*16+L
    float w2v[8];
    #pragma unroll
    for (int j = 0; j < 8; ++j) w2v[j] = W2[j * 16 + L];

    int si[4], di[4];
    #pragma unroll
    for (int i = 0; i < 4; ++i) { si[i] = src[eg + i]; di[i] = dst[eg + i]; }

    uint2 pu[4], pm[4];
    float scu[4], scm[4];
    #pragma unroll
    for (int i = 0; i < 4; ++i) {
        pu[i] = Pu[(size_t)si[i] * 16 + L];   // 8B/lane, one 128B line per 16-lane group
        pm[i] = Pm[(size_t)di[i] * 16 + L];
        scu[i] = SU[si[i]];                   // 400KB arrays, L2-resident
        scm[i] = SM[di[i]];
    }

    float res[4];
    #pragma unroll
    for (int i = 0; i < 4; ++i) {
        const unsigned int uw[2] = {pu[i].x, pu[i].y};
        const unsigned int mw[2] = {pm[i].x, pm[i].y};
        float acc = 0.0f;
        #pragma unroll
        for (int v = 0; v < 2; ++v) {
            #pragma unroll
            for (int k = 0; k < 4; ++k) {
                float h = fmaf(scu[i], i8f(uw[v], k), scm[i] * i8f(mw[v], k));
                acc = fmaf(fmaxf(h, 0.0f), w2v[v * 4 + k], acc);
            }
        }
        #pragma unroll
        for (int off = 1; off < 16; off <<= 1)
            acc += __shfl_xor(acc, off, 64);
        res[i] = acc;
    }

    if (L == 0) {
        float bb = b2[0];
        *(float4*)(out + eg) = make_float4(res[0] + bb, res[1] + bb, res[2] + bb, res[3] + bb);
    }
}

extern "C" void kernel_launch(void* const* d_in, const int* in_sizes, int n_in,
                              void* d_out, int out_size, void* d_ws, size_t ws_size,
                              hipStream_t stream) {
    const float* userf  = (const float*)d_in[0];
    const float* movief = (const float*)d_in[1];
    const int*   eidx   = (const int*)d_in[2];
    const float* W1     = (const float*)d_in[3];
    const float* b1     = (const float*)d_in[4];
    const float* W2     = (const float*)d_in[5];
    const float* b2     = (const float*)d_in[6];
    float* out = (float*)d_out;

    const int NU = in_sizes[0] / 128;   // 100000
    const int NM = in_sizes[1] / 128;   // 100000
    const int E  = in_sizes[2] / 2;     // 1000000

    // Workspace: Qu 12.8MB | Qm 12.8MB | SU 400KB | SM 400KB | WF 64KB
    uint2* Pu = (uint2*)d_ws;
    uint2* Pm = Pu + (size_t)NU * 16;
    float* SU = (float*)(Pm + (size_t)NM * 16);
    float* SM = SU + NU;
    uint4* WF = (uint4*)(SM + NM);

    const int ntiles = NU / 16;   // 6250 per half
    const int bph    = 512;       // blocks per half -> 2048 waves/half, ~3 tiles/wave

    pack_w<<<2, 256, 0, stream>>>(W1, WF);
    proj_kernel<<<2 * bph, 256, 0, stream>>>(userf, movief, WF, b1, Pu, Pm, SU, SM, ntiles, bph);
    edge_kernel<<<E / 64, 256, 0, stream>>>(eidx, eidx + E, Pu, Pm, SU, SM, W2, b2, out);
}

// Round 8
// 189.904 us; speedup vs baseline: 1.3762x; 1.0127x over previous
//
#include <hip/hip_runtime.h>
#include <hip/hip_bf16.h>

typedef short s8v __attribute__((ext_vector_type(8)));   // 8 bf16 (4 VGPRs) MFMA A/B frag
typedef float f4v __attribute__((ext_vector_type(4)));   // 4 fp32 MFMA C/D frag

__device__ __forceinline__ unsigned int bfround(float f) {
    unsigned int x = __float_as_uint(f);
    return (x + 0x7fffu + ((x >> 16) & 1u)) >> 16;  // RNE fp32->bf16
}
// packed RNE fp32x2 -> bf16x2 (v_cvt_pk_bf16_f32 on gfx950)
__device__ __forceinline__ unsigned int pkbf(float x, float y) {
    __hip_bfloat162 h = __float22bfloat162_rn(make_float2(x, y));
    return *(unsigned int*)&h;
}
// signed-int8 extract byte k of word w -> float  (v_bfe_i32 + v_cvt_f32_i32)
__device__ __forceinline__ float i8f(unsigned int w, int k) {
    return (float)((int)(signed char)(w >> (8 * k)));
}

// Pack W1 (fp32, [256x128]) into bf16 MFMA B-fragments laid out per-lane so proj
// waves read them with fully-coalesced uint4 loads.
// WF[half][c][t][lane] : uint4 = 8 bf16, j=0..7, k = c*32 + (lane>>4)*8 + j, col = t*16 + (lane&15)
__global__ __launch_bounds__(256) void pack_w(const float* __restrict__ W1,
                                              uint4* __restrict__ WF)
{
    const int half = blockIdx.x;
    #pragma unroll
    for (int iter = 0; iter < 8; ++iter) {
        int idx  = iter * 256 + threadIdx.x;   // (c,t,lane) flattened
        int lane = idx & 63;
        int t    = (idx >> 6) & 7;
        int c    = idx >> 9;
        int q = lane >> 4, m = lane & 15;
        unsigned int w[4];
        #pragma unroll
        for (int jj = 0; jj < 4; ++jj) {
            float lo = W1[(size_t)(half * 128 + c * 32 + q * 8 + 2 * jj    ) * 128 + t * 16 + m];
            float hi = W1[(size_t)(half * 128 + c * 32 + q * 8 + 2 * jj + 1) * 128 + t * 16 + m];
            w[jj] = bfround(lo) | (bfround(hi) << 16);
        }
        WF[(size_t)half * 2048 + idx] = make_uint4(w[0], w[1], w[2], w[3]);
    }
}

// Projection v4: LDS-staged A-tile, barrier-free (per-wave private LDS region).
// Stage 16x128 fp32 tile via 8 fully-coalesced 1KB loads -> bf16 -> LDS (pitch
// 288B = 72 dw; ds_read_b128 fragments see 4-way conflicts = 1.58x, cheap).
// Blocks [0,bph) = users, [bph,2*bph) = movies. int8 rows + per-row fp32 scale,
// column perm(t*16+m) = m*8+t (edge kernel indexes W2 identically).
__global__ __launch_bounds__(256) void proj_kernel(
    const float* __restrict__ userf, const float* __restrict__ movief,
    const uint4* __restrict__ WF, const float* __restrict__ b1,
    uint2* __restrict__ Pu, uint2* __restrict__ Pm,
    float* __restrict__ SU, float* __restrict__ SM,
    int ntiles, int bph)
{
    __shared__ __align__(16) unsigned int lds[4608];   // 4 waves x 16 rows x 72 dw = 18KB

    const int w    = threadIdx.x >> 6;
    const int lane = threadIdx.x & 63;
    const int half = blockIdx.x >= bph;
    const int bid  = half ? blockIdx.x - bph : blockIdx.x;
    const int tile = bid * 4 + w;
    if (tile >= ntiles) return;          // wave-uniform exit; kernel has no barriers

    const float* __restrict__ feat = half ? movief : userf;
    uint2* __restrict__ P = half ? Pm : Pu;
    float* __restrict__ S = half ? SM : SU;
    const uint4* __restrict__ wfh = WF + (size_t)half * 2048;

    unsigned int* wl = lds + w * 1152;   // this wave's private 16-row region

    // Stage: 8 lane-linear float4 loads (1KB contiguous per instruction),
    // pack to bf16 in-register, ds_write_b64 into padded rows.
    const float4* tbase = (const float4*)feat + (size_t)tile * 512;
    #pragma unroll
    for (int p = 0; p < 8; ++p) {
        float4 v = tbase[p * 64 + lane];
        int r  = (p * 64 + lane) >> 5;   // local row 0..15 (2 rows per instruction)
        int cc = lane & 31;              // float4-chunk within row (4 cols -> 2 dw bf16)
        *(uint2*)&wl[r * 72 + cc * 2] = make_uint2(pkbf(v.x, v.y), pkbf(v.z, v.w));
    }

    const int m = lane & 15;
    const int q = lane >> 4;

    f4v acc[8];
    #pragma unroll
    for (int t = 0; t < 8; ++t) {
        float bv = half ? b1[t * 16 + m] : 0.0f;
        acc[t] = (f4v){bv, bv, bv, bv};
    }

    #pragma unroll
    for (int c = 0; c < 4; ++c) {
        uint4 fr[8];
        #pragma unroll
        for (int t = 0; t < 8; ++t)
            fr[t] = wfh[(c * 8 + t) * 64 + lane];   // 64KB packed table, L1/L2-hot

        // A fragment: one ds_read_b128 (16B aligned: (72m + 16c + 4q)*4 % 16 == 0)
        s8v af = *(const s8v*)&wl[m * 72 + c * 16 + q * 4];

        #pragma unroll
        for (int t = 0; t < 8; ++t)
            acc[t] = __builtin_amdgcn_mfma_f32_16x16x32_bf16(af, *(const s8v*)&fr[t], acc[t], 0, 0, 0);
    }

    // C/D layout: col = t*16+m, row = q*4+r  [m89/m91 verified]. int8-quantize each
    // row; absmax over the 16-lane m-group (xor 1..8 stays in-group).
    #pragma unroll
    for (int r = 0; r < 4; ++r) {
        float mx = 0.0f;
        #pragma unroll
        for (int t = 0; t < 8; ++t) mx = fmaxf(mx, fabsf(acc[t][r]));
        #pragma unroll
        for (int off = 1; off < 16; off <<= 1)
            mx = fmaxf(mx, __shfl_xor(mx, off, 64));
        float inv = mx > 0.0f ? 127.0f / mx : 0.0f;

        unsigned int lo = 0, hi = 0;
        #pragma unroll
        for (int t = 0; t < 4; ++t) {
            lo |= ((unsigned int)(__float2int_rn(acc[t][r]     * inv) & 0xff)) << (8 * t);
            hi |= ((unsigned int)(__float2int_rn(acc[t + 4][r] * inv) & 0xff)) << (8 * t);
        }
        int row = tile * 16 + q * 4 + r;
        P[(size_t)row * 16 + m] = make_uint2(lo, hi);  // 16 lanes x 8B = one 128B row
        if (m == 0) S[row] = mx * (1.0f / 127.0f);
    }
}

// out[e] = relu(su*Qu[src] + sm*Qm[dst]) . W2 + b2   (b1 folded into Pm; perm'd dims)
// 16 lanes/edge (uint2 = 8 int8 dims per lane), 16 edges/wave.
__global__ __launch_bounds__(256) void edge_kernel(
    const int* __restrict__ src, const int* __restrict__ dst,
    const uint2* __restrict__ Pu, const uint2* __restrict__ Pm,
    const float* __restrict__ SU, const float* __restrict__ SM,
    const float* __restrict__ W2, const float* __restrict__ b2,
    float* __restrict__ out)
{
    const int lane = threadIdx.x & 63;
    const int L    = lane & 15;      // sub-lane within edge group
    const int g    = lane >> 4;      // edge group 0..3
    const int eg   = (blockIdx.x * 4 + (threadIdx.x >> 6)) * 16 + g * 4;

    // W2 at perm position L*8+j is original col j*16+L
    float w2v[8];
    #pragma unroll
    for (int j = 0; j < 8; ++j) w2v[j] = W2[j * 16 + L];

    int si[4], di[4];
    #pragma unroll
    for (int i = 0; i < 4; ++i) { si[i] = src[eg + i]; di[i] = dst[eg + i]; }

    uint2 pu[4], pm[4];
    float scu[4], scm[4];
    #pragma unroll
    for (int i = 0; i < 4; ++i) {
        pu[i] = Pu[(size_t)si[i] * 16 + L];   // 8B/lane, one 128B line per 16-lane group
        pm[i] = Pm[(size_t)di[i] * 16 + L];
        scu[i] = SU[si[i]];                   // 400KB arrays, L2-resident
        scm[i] = SM[di[i]];
    }

    float res[4];
    #pragma unroll
    for (int i = 0; i < 4; ++i) {
        const unsigned int uw[2] = {pu[i].x, pu[i].y};
        const unsigned int mw[2] = {pm[i].x, pm[i].y};
        float acc = 0.0f;
        #pragma unroll
        for (int v = 0; v < 2; ++v) {
            #pragma unroll
            for (int k = 0; k < 4; ++k) {
                float h = fmaf(scu[i], i8f(uw[v], k), scm[i] * i8f(mw[v], k));
                acc = fmaf(fmaxf(h, 0.0f), w2v[v * 4 + k], acc);
            }
        }
        #pragma unroll
        for (int off = 1; off < 16; off <<= 1)
            acc += __shfl_xor(acc, off, 64);
        res[i] = acc;
    }

    if (L == 0) {
        float bb = b2[0];
        *(float4*)(out + eg) = make_float4(res[0] + bb, res[1] + bb, res[2] + bb, res[3] + bb);
    }
}

extern "C" void kernel_launch(void* const* d_in, const int* in_sizes, int n_in,
                              void* d_out, int out_size, void* d_ws, size_t ws_size,
                              hipStream_t stream) {
    const float* userf  = (const float*)d_in[0];
    const float* movief = (const float*)d_in[1];
    const int*   eidx   = (const int*)d_in[2];
    const float* W1     = (const float*)d_in[3];
    const float* b1     = (const float*)d_in[4];
    const float* W2     = (const float*)d_in[5];
    const float* b2     = (const float*)d_in[6];
    float* out = (float*)d_out;

    const int NU = in_sizes[0] / 128;   // 100000
    const int NM = in_sizes[1] / 128;   // 100000
    const int E  = in_sizes[2] / 2;     // 1000000

    // Workspace: Qu 12.8MB | Qm 12.8MB | SU 400KB | SM 400KB | WF 64KB
    uint2* Pu = (uint2*)d_ws;
    uint2* Pm = Pu + (size_t)NU * 16;
    float* SU = (float*)(Pm + (size_t)NM * 16);
    float* SM = SU + NU;
    uint4* WF = (uint4*)(SM + NM);

    const int ntiles = NU / 16;              // 6250 per half
    const int bph    = (ntiles + 3) / 4;     // 1563 blocks per half (4 tiles/block)

    pack_w<<<2, 256, 0, stream>>>(W1, WF);
    proj_kernel<<<2 * bph, 256, 0, stream>>>(userf, movief, WF, b1, Pu, Pm, SU, SM, ntiles, bph);
    edge_kernel<<<E / 64, 256, 0, stream>>>(eidx, eidx + E, Pu, Pm, SU, SM, W2, b2, out);
}

// Round 9
// 184.906 us; speedup vs baseline: 1.4134x; 1.0270x over previous
//
#include <hip/hip_runtime.h>
#include <hip/hip_bf16.h>

typedef short s8v __attribute__((ext_vector_type(8)));   // 8 bf16 (4 VGPRs) MFMA A/B frag
typedef float f4v __attribute__((ext_vector_type(4)));   // 4 fp32 MFMA C/D frag

__device__ __forceinline__ unsigned int bfround(float f) {
    unsigned int x = __float_as_uint(f);
    return (x + 0x7fffu + ((x >> 16) & 1u)) >> 16;  // RNE fp32->bf16
}
// packed RNE fp32x2 -> bf16x2 (v_cvt_pk_bf16_f32 on gfx950)
__device__ __forceinline__ unsigned int pkbf(float x, float y) {
    __hip_bfloat162 h = __float22bfloat162_rn(make_float2(x, y));
    return *(unsigned int*)&h;
}
// signed-int8 extract byte k of word w -> float  (v_bfe_i32 + v_cvt_f32_i32)
__device__ __forceinline__ float i8f(unsigned int w, int k) {
    return (float)((int)(signed char)(w >> (8 * k)));
}

// Pack W1 (fp32, [256x128]) into bf16 MFMA B-fragments laid out per-lane so proj
// waves read them with fully-coalesced uint4 loads.
// WF[half][c][t][lane] : uint4 = 8 bf16, j=0..7, k = c*32 + (lane>>4)*8 + j, col = t*16 + (lane&15)
__global__ __launch_bounds__(256) void pack_w(const float* __restrict__ W1,
                                              uint4* __restrict__ WF)
{
    const int half = blockIdx.x;
    #pragma unroll
    for (int iter = 0; iter < 8; ++iter) {
        int idx  = iter * 256 + threadIdx.x;   // (c,t,lane) flattened
        int lane = idx & 63;
        int t    = (idx >> 6) & 7;
        int c    = idx >> 9;
        int q = lane >> 4, m = lane & 15;
        unsigned int w[4];
        #pragma unroll
        for (int jj = 0; jj < 4; ++jj) {
            float lo = W1[(size_t)(half * 128 + c * 32 + q * 8 + 2 * jj    ) * 128 + t * 16 + m];
            float hi = W1[(size_t)(half * 128 + c * 32 + q * 8 + 2 * jj + 1) * 128 + t * 16 + m];
            w[jj] = bfround(lo) | (bfround(hi) << 16);
        }
        WF[(size_t)half * 2048 + idx] = make_uint4(w[0], w[1], w[2], w[3]);
    }
}

// Projection v5: persistent waves; W fragments loaded ONCE per wave (coalesced,
// from packed WF) and held in registers for all tiles; A prefetched one tile
// ahead. Tile loop has zero W traffic. Blocks [0,bph)=users, [bph,2bph)=movies.
// int8 rows + per-row fp32 scale, column perm(t*16+m) = m*8+t.
__global__ __launch_bounds__(256, 2) void proj_kernel(
    const float* __restrict__ userf, const float* __restrict__ movief,
    const uint4* __restrict__ WF, const float* __restrict__ b1,
    uint2* __restrict__ Pu, uint2* __restrict__ Pm,
    float* __restrict__ SU, float* __restrict__ SM,
    int ntiles, int bph)
{
    const int half = blockIdx.x >= bph;
    const int bid  = half ? blockIdx.x - bph : blockIdx.x;
    const float* __restrict__ feat = half ? movief : userf;
    uint2* __restrict__ P = half ? Pm : Pu;
    float* __restrict__ S = half ? SM : SU;
    const uint4* __restrict__ wfh = WF + (size_t)half * 2048;

    const int lane = threadIdx.x & 63;
    const int m    = lane & 15;
    const int q    = lane >> 4;

    // One-time: all 32 B-fragments, 32 coalesced uint4 loads -> 128 VGPRs.
    s8v bfrag[8][4];
    #pragma unroll
    for (int c = 0; c < 4; ++c)
        #pragma unroll
        for (int t = 0; t < 8; ++t) {
            uint4 f = wfh[(c * 8 + t) * 64 + lane];
            bfrag[t][c] = *(const s8v*)&f;
        }

    float bias_v[8];
    #pragma unroll
    for (int t = 0; t < 8; ++t)
        bias_v[t] = half ? b1[t * 16 + m] : 0.0f;

    const int wid = bid * 4 + (threadIdx.x >> 6);   // wave id within half
    const int nw  = bph * 4;                        // waves per half

#define LOAD_A(dst, t_) do {                                            \
        const float4* arow_ = (const float4*)feat + (size_t)(t_) * 512; \
        _Pragma("unroll")                                               \
        for (int c_ = 0; c_ < 4; ++c_) {                                \
            dst[c_][0] = arow_[m * 32 + c_ * 8 + q * 2 + 0];            \
            dst[c_][1] = arow_[m * 32 + c_ * 8 + q * 2 + 1];            \
        }                                                               \
    } while (0)

    float4 a[4][2];
    int tile = wid;
    if (tile < ntiles) LOAD_A(a, tile);

    while (tile < ntiles) {
        const int nxt = tile + nw;
        float4 an[4][2];
        if (nxt < ntiles) LOAD_A(an, nxt);   // in flight across this tile's compute

        f4v acc[8];
        #pragma unroll
        for (int t = 0; t < 8; ++t)
            acc[t] = (f4v){bias_v[t], bias_v[t], bias_v[t], bias_v[t]};

        #pragma unroll
        for (int c = 0; c < 4; ++c) {
            uint4 aw;
            aw.x = pkbf(a[c][0].x, a[c][0].y);
            aw.y = pkbf(a[c][0].z, a[c][0].w);
            aw.z = pkbf(a[c][1].x, a[c][1].y);
            aw.w = pkbf(a[c][1].z, a[c][1].w);
            s8v af = *(const s8v*)&aw;

            #pragma unroll
            for (int t = 0; t < 8; ++t)
                acc[t] = __builtin_amdgcn_mfma_f32_16x16x32_bf16(af, bfrag[t][c], acc[t], 0, 0, 0);
        }

        // C/D layout: col = t*16+m, row = q*4+r  [m89/m91 verified]. int8-quantize
        // each row; absmax over the 16-lane m-group (xor 1..8 stays in-group).
        #pragma unroll
        for (int r = 0; r < 4; ++r) {
            float mx = 0.0f;
            #pragma unroll
            for (int t = 0; t < 8; ++t) mx = fmaxf(mx, fabsf(acc[t][r]));
            #pragma unroll
            for (int off = 1; off < 16; off <<= 1)
                mx = fmaxf(mx, __shfl_xor(mx, off, 64));
            float inv = mx > 0.0f ? 127.0f / mx : 0.0f;

            unsigned int lo = 0, hi = 0;
            #pragma unroll
            for (int t = 0; t < 4; ++t) {
                lo |= ((unsigned int)(__float2int_rn(acc[t][r]     * inv) & 0xff)) << (8 * t);
                hi |= ((unsigned int)(__float2int_rn(acc[t + 4][r] * inv) & 0xff)) << (8 * t);
            }
            int row = tile * 16 + q * 4 + r;
            P[(size_t)row * 16 + m] = make_uint2(lo, hi);  // 16 lanes x 8B = one 128B row
            if (m == 0) S[row] = mx * (1.0f / 127.0f);
        }

        #pragma unroll
        for (int c = 0; c < 4; ++c) {
            a[c][0] = an[c][0];
            a[c][1] = an[c][1];
        }
        tile = nxt;
    }
#undef LOAD_A
}

// out[e] = relu(su*Qu[src] + sm*Qm[dst]) . W2 + b2   (b1 folded into Pm; perm'd dims)
// 16 lanes/edge (uint2 = 8 int8 dims per lane), 16 edges/wave.
__global__ __launch_bounds__(256) void edge_kernel(
    const int* __restrict__ src, const int* __restrict__ dst,
    const uint2* __restrict__ Pu, const uint2* __restrict__ Pm,
    const float* __restrict__ SU, const float* __restrict__ SM,
    const float* __restrict__ W2, const float* __restrict__ b2,
    float* __restrict__ out)
{
    const int lane = threadIdx.x & 63;
    const int L    = lane & 15;      // sub-lane within edge group
    const int g    = lane >> 4;      // edge group 0..3
    const int eg   = (blockIdx.x * 4 + (threadIdx.x >> 6)) * 16 + g * 4;

    // W2 at perm position L*8+j is original col j*16+L
    float w2v[8];
    #pragma unroll
    for (int j = 0; j < 8; ++j) w2v[j] = W2[j * 16 + L];

    int si[4], di[4];
    #pragma unroll
    for (int i = 0; i < 4; ++i) { si[i] = src[eg + i]; di[i] = dst[eg + i]; }

    uint2 pu[4], pm[4];
    float scu[4], scm[4];
    #pragma unroll
    for (int i = 0; i < 4; ++i) {
        pu[i] = Pu[(size_t)si[i] * 16 + L];   // 8B/lane, one 128B line per 16-lane group
        pm[i] = Pm[(size_t)di[i] * 16 + L];
        scu[i] = SU[si[i]];                   // 400KB arrays, L2-resident
        scm[i] = SM[di[i]];
    }

    float res[4];
    #pragma unroll
    for (int i = 0; i < 4; ++i) {
        const unsigned int uw[2] = {pu[i].x, pu[i].y};
        const unsigned int mw[2] = {pm[i].x, pm[i].y};
        float acc = 0.0f;
        #pragma unroll
        for (int v = 0; v < 2; ++v) {
            #pragma unroll
            for (int k = 0; k < 4; ++k) {
                float h = fmaf(scu[i], i8f(uw[v], k), scm[i] * i8f(mw[v], k));
                acc = fmaf(fmaxf(h, 0.0f), w2v[v * 4 + k], acc);
            }
        }
        #pragma unroll
        for (int off = 1; off < 16; off <<= 1)
            acc += __shfl_xor(acc, off, 64);
        res[i] = acc;
    }

    if (L == 0) {
        float bb = b2[0];
        *(float4*)(out + eg) = make_float4(res[0] + bb, res[1] + bb, res[2] + bb, res[3] + bb);
    }
}

extern "C" void kernel_launch(void* const* d_in, const int* in_sizes, int n_in,
                              void* d_out, int out_size, void* d_ws, size_t ws_size,
                              hipStream_t stream) {
    const float* userf  = (const float*)d_in[0];
    const float* movief = (const float*)d_in[1];
    const int*   eidx   = (const int*)d_in[2];
    const float* W1     = (const float*)d_in[3];
    const float* b1     = (const float*)d_in[4];
    const float* W2     = (const float*)d_in[5];
    const float* b2     = (const float*)d_in[6];
    float* out = (float*)d_out;

    const int NU = in_sizes[0] / 128;   // 100000
    const int NM = in_sizes[1] / 128;   // 100000
    const int E  = in_sizes[2] / 2;     // 1000000

    // Workspace: Qu 12.8MB | Qm 12.8MB | SU 400KB | SM 400KB | WF 64KB
    uint2* Pu = (uint2*)d_ws;
    uint2* Pm = Pu + (size_t)NU * 16;
    float* SU = (float*)(Pm + (size_t)NM * 16);
    float* SM = SU + NU;
    uint4* WF = (uint4*)(SM + NM);

    const int ntiles = NU / 16;   // 6250 per half
    const int bph    = 512;       // 2048 waves/half, ~3 tiles/wave

    pack_w<<<2, 256, 0, stream>>>(W1, WF);
    proj_kernel<<<2 * bph, 256, 0, stream>>>(userf, movief, WF, b1, Pu, Pm, SU, SM, ntiles, bph);
    edge_kernel<<<E / 64, 256, 0, stream>>>(eidx, eidx + E, Pu, Pm, SU, SM, W2, b2, out);
}